// Round 11
// baseline (23.527 us; speedup 1.0000x reference)
//
#include <hip/hip_runtime.h>
#include <math.h>

#define NCOL 22
#define NEMB 12
#define D 64
#define BB 2048
#define NPAIR (NCOL*NCOL)   // 484
#define REGC 0.001f

__device__ __forceinline__ float ftanh(float x) {
    float cx = fminf(fmaxf(x, -10.f), 10.f);
    float e = __expf(2.f * cx);
    return (e - 1.f) / (e + 1.f);
}

// ---------------------------------------------------------------------------
// k_build: 990 blocks x 384 threads.
// Blocks 0..967: (pair, d-half). Stage the 12x32 d-slice of trans rows i and
// j (2 MLP evals/thread via strided loop), pack the half's pair weights,
// diag blocks fold the half's linear weights, then 288 threads = 144 combos
// x 2 sub-slices (16-deep) -> LDS combine -> write this half's float2 of
// ptab4[pair][combo]. Blocks 968..989: column norms -> cn[i].
// ---------------------------------------------------------------------------
__global__ __launch_bounds__(384) void k_build(
    const int* __restrict__ features, const float* __restrict__ tables,
    const float* __restrict__ w1, const float* __restrict__ b1,
    const float* __restrict__ w2, const float* __restrict__ b2,
    const float* __restrict__ W_ops, const float* __restrict__ W_concat,
    const float* __restrict__ aw,
    float2* __restrict__ ptab2, float* __restrict__ cn)
{
    int bid = blockIdx.x, tid = threadIdx.x;

    if (bid >= 2 * NPAIR) {             // ---- column-norm blocks ----
        int i = bid - 2 * NPAIR;
        __shared__ float ssq[NEMB];
        __shared__ float parts[6];
        if (tid < NEMB) {
            const float* tp = tables + (i * NEMB + tid) * D;
            float s = 0.f;
            #pragma unroll
            for (int d = 0; d < D; ++d) s = fmaf(tp[d], tp[d], s);
            ssq[tid] = s;
        }
        __syncthreads();
        float s = 0.f;
        for (int k = tid; k < BB; k += 384) s += ssq[features[i * BB + k]];
        #pragma unroll
        for (int m = 32; m; m >>= 1) s += __shfl_xor(s, m);
        if ((tid & 63) == 0) parts[tid >> 6] = s;
        __syncthreads();
        if (tid == 0) {
            float t = 0.f;
            #pragma unroll
            for (int q = 0; q < 6; ++q) t += parts[q];
            cn[i] = sqrtf(t);
        }
        return;
    }

    // ---- pair-half blocks ----
    int pair = bid >> 1, h = bid & 1;
    int i = pair / NCOL, j = pair - (pair / NCOL) * NCOL;
    bool diag = (i == j);
    int dbase = h * 32;                   // this block's d-slice [dbase, dbase+32)

    __shared__ float ti[NEMB][33];        // 12 x 32 slice (+1 pad)
    __shared__ float tj[NEMB][33];
    __shared__ float4 w4s[32];
    __shared__ float wls[2][32];
    __shared__ float2 comb[144][2];

    float b2v = b2[0];
    float a0 = aw[0], a1 = aw[1], a2 = aw[2], a3 = aw[3], a4 = aw[4];
    const float* Wm   = W_ops + 1 * NPAIR * 2 * D;
    const float* Wmax = W_ops + 2 * NPAIR * 2 * D;
    const float* Wmin = W_ops + 3 * NPAIR * 2 * D;

    // stage the d-slice of trans rows i and j: 768 evals, 2 per thread
    for (int k = tid; k < 2 * NEMB * 32; k += 384) {
        int half = (k >= NEMB * 32);
        int kk = k - half * NEMB * 32;         // [0, 384): e*32 + dd
        int e = kk >> 5, dd = kk & 31;
        float x = tables[(half ? j : i) * NEMB * D + e * D + dbase + dd];
        float acc = b2v;
        #pragma unroll
        for (int hh = 0; hh < 8; ++hh)
            acc = fmaf(ftanh(fmaf(x, w1[hh], b1[hh])), w2[hh], acc);
        (half ? tj : ti)[e][dd] = acc;
    }

    // pack this half's pair weights (threads 0..31)
    if (tid < 32) {
        int d = dbase + tid;
        int i0 = (pair * 2 + 0) * D + d;
        int i1 = (pair * 2 + 1) * D + d;
        float4 v;
        v.x = a1 * Wm[i0];
        v.y = a1 * Wm[i1];
        v.z = 0.5f * (a2 * Wmax[i0] - a3 * Wmin[i0]);
        v.w = 0.5f * (a2 * Wmax[i1] - a3 * Wmin[i1]);
        w4s[tid] = v;
    }

    // diagonal blocks fold this half's linear weights (threads 64..127)
    if (diag && tid >= 64 && tid < 128) {
        int t = tid - 64;
        int o = t >> 5, dd = t & 31;
        int d = dbase + dd;
        float lp = 0.f, lc = 0.f, lmm = 0.f;
        #pragma unroll
        for (int jj = 0; jj < NCOL; ++jj) {
            int ij = ((i * NCOL + jj) * 2 + o) * D + d;
            int ji = ((jj * NCOL + i) * 2 + o) * D + d;
            lp += W_ops[ij] + W_ops[ji];
            lc += W_concat[((i * NCOL + jj) * 2 + o) * 2 * D + d]
                + W_concat[((jj * NCOL + i) * 2 + o) * 2 * D + D + d];
            lmm += a2 * (Wmax[ij] + Wmax[ji]) + a3 * (Wmin[ij] + Wmin[ji]);
        }
        wls[o][dd] = a0 * lp + a4 * lc + 0.5f * lmm;
    }
    __syncthreads();

    // combos: 288 threads = 144 combos x 2 sub-slices (16-deep each)
    if (tid < 288) {
        int c = tid >> 1, sub = tid & 1;
        int ei = c / NEMB, ej = c - (c / NEMB) * NEMB;
        int d0 = sub * 16;
        bool dl = diag & (ei == ej);
        float r0 = 0.f, r1 = 0.f, l0 = 0.f, l1 = 0.f;
        #pragma unroll
        for (int dd = d0; dd < d0 + 16; ++dd) {
            float a = ti[ei][dd], b = tj[ej][dd];
            float4 w4 = w4s[dd];
            float pp = a * b, dfa = fabsf(a - b);
            r0 = fmaf(pp, w4.x, fmaf(dfa, w4.z, r0));
            r1 = fmaf(pp, w4.y, fmaf(dfa, w4.w, r1));
            if (dl) {
                l0 = fmaf(a, wls[0][dd], l0);
                l1 = fmaf(a, wls[1][dd], l1);
            }
        }
        comb[c][sub] = make_float2(r0 + l0, r1 + l1);
    }
    __syncthreads();
    // combine sub-slices; write this half's float2 of the float4 element
    if (tid < 144) {
        float2 u = comb[tid][0], v = comb[tid][1];
        ptab2[(pair * 144 + tid) * 2 + h] = make_float2(u.x + v.x, u.y + v.y);
    }
}

// ---------------------------------------------------------------------------
// k_gather: 1024 blocks x 2 b's (4 blocks/CU). Thread (g,b): g = tid>>1 in
// [0,128) sums ~4 pairs (one float4 load each = both halves); shuffle-reduce
// the 32 g's per wave, LDS-reduce the 4 waves. Block 0 writes the reg scalar.
// ---------------------------------------------------------------------------
__global__ __launch_bounds__(256) void k_gather(const int* __restrict__ features,
        const float4* __restrict__ ptab4, const float* __restrict__ cn,
        float* __restrict__ out)
{
    __shared__ int fs[NCOL][2];
    __shared__ float red[4][2][2];
    int tid = threadIdx.x;
    int b0 = blockIdx.x * 2;

    if (tid < NCOL * 2) {
        int i = tid >> 1, q = tid & 1;
        fs[i][q] = features[i * BB + b0 + q];
    }
    __syncthreads();

    int b = tid & 1, g = tid >> 1;              // 128 pair-groups x 2 b's
    int p0 = (g * NPAIR) >> 7, p1 = ((g + 1) * NPAIR) >> 7;
    float a0 = 0.f, a1 = 0.f;
    #pragma unroll 2
    for (int p = p0; p < p1; ++p) {
        int i = (p * 2979) >> 16;               // exact p/22 for p < 484
        int j = p - i * NCOL;
        float4 v = ptab4[p * 144 + fs[i][b] * NEMB + fs[j][b]];
        a0 += v.x + v.z;
        a1 += v.y + v.w;
    }
    // reduce the 32 g's within each wave (lanes differing in bits 1..5)
    #pragma unroll
    for (int m = 2; m <= 32; m <<= 1) {
        a0 += __shfl_xor(a0, m);
        a1 += __shfl_xor(a1, m);
    }
    int w = tid >> 6, lane = tid & 63;
    if (lane < 2) {
        red[w][lane][0] = a0;
        red[w][lane][1] = a1;
    }
    __syncthreads();
    if (tid < 4) {
        int bb = tid >> 1, o = tid & 1;
        out[(b0 + bb) * 2 + o] = red[0][bb][o] + red[1][bb][o]
                               + red[2][bb][o] + red[3][bb][o];
    }
    if (blockIdx.x == 0 && tid == 64) {
        float s = 0.f;
        for (int c = 0; c < NCOL; ++c) s += cn[c];
        out[BB * 2] = REGC * (2.0f * NCOL) * s;
    }
}

extern "C" void kernel_launch(void* const* d_in, const int* in_sizes, int n_in,
                              void* d_out, int out_size, void* d_ws, size_t ws_size,
                              hipStream_t stream) {
    const int*   features = (const int*)d_in[0];
    const float* tables   = (const float*)d_in[1];
    const float* w1       = (const float*)d_in[2];
    const float* b1       = (const float*)d_in[3];
    const float* w2       = (const float*)d_in[4];
    const float* b2       = (const float*)d_in[5];
    const float* W_ops    = (const float*)d_in[6];
    const float* W_concat = (const float*)d_in[7];
    const float* aw       = (const float*)d_in[8];
    float* out = (float*)d_out;
    char*  ws  = (char*)d_ws;

    float2* ptab2 = (float2*)ws;                   // 484*144 float4 = 1,115,136 B
    float*  cn    = (float*)(ws + 1115136);        // 22 f

    k_build <<<dim3(2 * NPAIR + NCOL), dim3(384), 0, stream>>>(
        features, tables, w1, b1, w2, b2, W_ops, W_concat, aw, ptab2, cn);
    k_gather<<<dim3(1024), dim3(256), 0, stream>>>(
        features, (const float4*)ws, cn, out);
}

// Round 14
// 22.164 us; speedup vs baseline: 1.0615x; 1.0615x over previous
//
#include <hip/hip_runtime.h>
#include <math.h>

#define NCOL 22
#define NEMB 12
#define D 64
#define BB 2048
#define NUP 253             // unordered pairs incl. diagonal: 22*23/2 = 253
#define REGC 0.001f

__device__ __forceinline__ float ftanh(float x) {
    float cx = fminf(fmaxf(x, -10.f), 10.f);
    float e = __expf(2.f * cx);
    return (e - 1.f) / (e + 1.f);
}

// p -> (i,j), i<=j, triangular-with-diagonal order (p in [0,253))
__device__ __forceinline__ void up_ij(int p, int& io, int& jo) {
    int s = 0, i = 0, j = 0;
    #pragma unroll
    for (int k = 0; k < NCOL; ++k) {
        int rl = NCOL - k;
        if (p >= s && p < s + rl) { i = k; j = k + (p - s); }
        s += rl;
    }
    io = i; jo = j;
}

// ---------------------------------------------------------------------------
// k_build: 275 blocks x 384 threads.
// Blocks 0..252: unordered pair (i<=j). Stage trans rows i,j (full d, 4 MLP
// evals/thread), pack FOLDED pair weights (W[ij]+W[ji] off-diag), diag blocks
// fold linear weights, 288-thread combo (2 x 32-deep halves) -> ptab.
// Blocks 253..274: column norms -> cn.
// ---------------------------------------------------------------------------
__global__ __launch_bounds__(384) void k_build(
    const int* __restrict__ features, const float* __restrict__ tables,
    const float* __restrict__ w1, const float* __restrict__ b1,
    const float* __restrict__ w2, const float* __restrict__ b2,
    const float* __restrict__ W_ops, const float* __restrict__ W_concat,
    const float* __restrict__ aw,
    float2* __restrict__ ptab, float* __restrict__ cn)
{
    int bid = blockIdx.x, tid = threadIdx.x;

    if (bid >= NUP) {                   // ---- column-norm blocks ----
        int i = bid - NUP;
        __shared__ float ssq[NEMB];
        __shared__ float parts[6];
        if (tid < NEMB) {
            const float* tp = tables + (i * NEMB + tid) * D;
            float s = 0.f;
            #pragma unroll
            for (int d = 0; d < D; ++d) s = fmaf(tp[d], tp[d], s);
            ssq[tid] = s;
        }
        __syncthreads();
        float s = 0.f;
        for (int k = tid; k < BB; k += 384) s += ssq[features[i * BB + k]];
        #pragma unroll
        for (int m = 32; m; m >>= 1) s += __shfl_xor(s, m);
        if ((tid & 63) == 0) parts[tid >> 6] = s;
        __syncthreads();
        if (tid == 0) {
            float t = 0.f;
            #pragma unroll
            for (int q = 0; q < 6; ++q) t += parts[q];
            cn[i] = sqrtf(t);
        }
        return;
    }

    // ---- pair blocks ----
    int i, j;
    up_ij(bid, i, j);
    bool diag = (i == j);
    __shared__ float ti[NEMB * 65];
    __shared__ float tj[NEMB * 65];
    __shared__ float4 w4s[D];
    __shared__ float wls[2 * D];
    __shared__ float2 comb[144][2];

    float b2v = b2[0];
    float a0 = aw[0], a1 = aw[1], a2 = aw[2], a3 = aw[3], a4 = aw[4];
    const float* Wm   = W_ops + 1 * NCOL * NCOL * 2 * D;
    const float* Wmax = W_ops + 2 * NCOL * NCOL * 2 * D;
    const float* Wmin = W_ops + 3 * NCOL * NCOL * 2 * D;

    // stage trans rows i and j (full d): 1536 evals, 4 per thread
    for (int k = tid; k < 2 * NEMB * D; k += 384) {
        int half = (k >= NEMB * D);
        int kk = k - half * NEMB * D;
        float x = tables[(half ? j : i) * NEMB * D + kk];
        float acc = b2v;
        #pragma unroll
        for (int h = 0; h < 8; ++h)
            acc = fmaf(ftanh(fmaf(x, w1[h], b1[h])), w2[h], acc);
        (half ? tj : ti)[(kk >> 6) * 65 + (kk & 63)] = acc;
    }

    // pack FOLDED pair weights (threads 0..63)
    if (tid < D) {
        int pij = i * NCOL + j, pji = j * NCOL + i;
        int a_ij = (pij * 2 + 0) * D + tid, b_ij = (pij * 2 + 1) * D + tid;
        float4 v;
        if (diag) {
            v.x = a1 * Wm[a_ij];
            v.y = a1 * Wm[b_ij];
            v.z = 0.5f * (a2 * Wmax[a_ij] - a3 * Wmin[a_ij]);
            v.w = 0.5f * (a2 * Wmax[b_ij] - a3 * Wmin[b_ij]);
        } else {
            int a_ji = (pji * 2 + 0) * D + tid, b_ji = (pji * 2 + 1) * D + tid;
            v.x = a1 * (Wm[a_ij] + Wm[a_ji]);
            v.y = a1 * (Wm[b_ij] + Wm[b_ji]);
            v.z = 0.5f * (a2 * (Wmax[a_ij] + Wmax[a_ji])
                        - a3 * (Wmin[a_ij] + Wmin[a_ji]));
            v.w = 0.5f * (a2 * (Wmax[b_ij] + Wmax[b_ji])
                        - a3 * (Wmin[b_ij] + Wmin[b_ji]));
        }
        w4s[tid] = v;
    }

    // diagonal blocks fold the linear weights (threads 64..191)
    if (diag && tid >= 64 && tid < 192) {
        int t = tid - 64;
        int o = t >> 6, d = t & 63;
        float lp = 0.f, lc = 0.f, lmm = 0.f;
        #pragma unroll
        for (int jj = 0; jj < NCOL; ++jj) {
            int ij = ((i * NCOL + jj) * 2 + o) * D + d;
            int ji = ((jj * NCOL + i) * 2 + o) * D + d;
            lp += W_ops[ij] + W_ops[ji];
            lc += W_concat[((i * NCOL + jj) * 2 + o) * 2 * D + d]
                + W_concat[((jj * NCOL + i) * 2 + o) * 2 * D + D + d];
            lmm += a2 * (Wmax[ij] + Wmax[ji]) + a3 * (Wmin[ij] + Wmin[ji]);
        }
        wls[o * D + d] = a0 * lp + a4 * lc + 0.5f * lmm;
    }
    __syncthreads();

    // combos: 288 threads = 144 combos x 2 halves of d (32-deep)
    if (tid < 288) {
        int c = tid >> 1, half = tid & 1;
        int ei = c / NEMB, ej = c - (c / NEMB) * NEMB;
        int d0 = half * 32;
        bool dl = diag & (ei == ej);
        float r0 = 0.f, r1 = 0.f, l0 = 0.f, l1 = 0.f;
        #pragma unroll 8
        for (int d = d0; d < d0 + 32; ++d) {
            float a = ti[ei * 65 + d], b = tj[ej * 65 + d];
            float4 w4 = w4s[d];
            float pp = a * b, dfa = fabsf(a - b);
            r0 = fmaf(pp, w4.x, fmaf(dfa, w4.z, r0));
            r1 = fmaf(pp, w4.y, fmaf(dfa, w4.w, r1));
            if (dl) {
                l0 = fmaf(a, wls[d], l0);
                l1 = fmaf(a, wls[D + d], l1);
            }
        }
        comb[c][half] = make_float2(r0 + l0, r1 + l1);
    }
    __syncthreads();
    if (tid < 144) {
        float2 u = comb[tid][0], v = comb[tid][1];
        ptab[bid * 144 + tid] = make_float2(u.x + v.x, u.y + v.y);
    }
}

// ---------------------------------------------------------------------------
// k_gather: 512 blocks x 4 b's (2 blocks/CU). Thread (g,b): g = tid>>2 in
// [0,64) sums its ~4 unordered pairs; shuffle-reduce the 16 g's per wave,
// LDS-reduce the 4 waves. Block 0 writes the reg scalar.
// ---------------------------------------------------------------------------
__global__ __launch_bounds__(256) void k_gather(const int* __restrict__ features,
        const float2* __restrict__ ptab, const float* __restrict__ cn,
        float* __restrict__ out)
{
    __shared__ int fs[NCOL][4];
    __shared__ float red[4][4][2];
    __shared__ int lip[NUP], ljp[NUP];
    int tid = threadIdx.x;
    int b0 = blockIdx.x * 4;

    for (int p = tid; p < NUP; p += 256) {
        int ii, jj;
        up_ij(p, ii, jj);
        lip[p] = ii; ljp[p] = jj;
    }
    if (tid >= 256 - NCOL * 4) {              // threads 168..255 stage features
        int k = tid - (256 - NCOL * 4);
        int i = k >> 2, q = k & 3;
        fs[i][q] = features[i * BB + b0 + q];
    }
    __syncthreads();

    int b = tid & 3, g = tid >> 2;            // 64 pair-groups x 4 b's
    int p0 = (g * NUP) >> 6, p1 = ((g + 1) * NUP) >> 6;
    float a0 = 0.f, a1 = 0.f;
    #pragma unroll 2
    for (int p = p0; p < p1; ++p) {
        float2 v = ptab[p * 144 + fs[lip[p]][b] * NEMB + fs[ljp[p]][b]];
        a0 += v.x; a1 += v.y;
    }
    // reduce the 16 g's within each wave (lanes differing in bits 2..5)
    #pragma unroll
    for (int m = 4; m <= 32; m <<= 1) {
        a0 += __shfl_xor(a0, m);
        a1 += __shfl_xor(a1, m);
    }
    int w = tid >> 6, lane = tid & 63;
    if (lane < 4) {
        red[w][lane][0] = a0;
        red[w][lane][1] = a1;
    }
    __syncthreads();
    if (tid < 8) {
        int bb = tid >> 1, o = tid & 1;
        out[(b0 + bb) * 2 + o] = red[0][bb][o] + red[1][bb][o]
                               + red[2][bb][o] + red[3][bb][o];
    }
    if (blockIdx.x == 0 && tid == 64) {
        float s = 0.f;
        for (int c = 0; c < NCOL; ++c) s += cn[c];
        out[BB * 2] = REGC * (2.0f * NCOL) * s;
    }
}

extern "C" void kernel_launch(void* const* d_in, const int* in_sizes, int n_in,
                              void* d_out, int out_size, void* d_ws, size_t ws_size,
                              hipStream_t stream) {
    const int*   features = (const int*)d_in[0];
    const float* tables   = (const float*)d_in[1];
    const float* w1       = (const float*)d_in[2];
    const float* b1       = (const float*)d_in[3];
    const float* w2       = (const float*)d_in[4];
    const float* b2       = (const float*)d_in[5];
    const float* W_ops    = (const float*)d_in[6];
    const float* W_concat = (const float*)d_in[7];
    const float* aw       = (const float*)d_in[8];
    float* out = (float*)d_out;
    char*  ws  = (char*)d_ws;

    float2* ptab = (float2*)ws;                    // 253*144*8 = 291,456 B
    float*  cn   = (float*)(ws + 291456);          // 22 f

    k_build <<<dim3(NUP + NCOL), dim3(384), 0, stream>>>(
        features, tables, w1, b1, w2, b2, W_ops, W_concat, aw, ptab, cn);
    k_gather<<<dim3(512), dim3(256), 0, stream>>>(features, ptab, cn, out);
}

// Round 15
// 19.273 us; speedup vs baseline: 1.2208x; 1.1500x over previous
//
#include <hip/hip_runtime.h>
#include <math.h>

#define NCOL 22
#define NEMB 12
#define D 64
#define BB 2048
#define NUP 253             // unordered pairs incl. diagonal: 22*23/2
#define REGC 0.001f

__device__ __forceinline__ float ftanh(float x) {
    float cx = fminf(fmaxf(x, -10.f), 10.f);
    float e = __expf(2.f * cx);
    return (e - 1.f) / (e + 1.f);
}

// p -> (i,j), i<=j, triangular-with-diagonal order (p in [0,253))
__device__ __forceinline__ void up_ij(int p, int& io, int& jo) {
    int s = 0, i = 0, j = 0;
    #pragma unroll
    for (int k = 0; k < NCOL; ++k) {
        int rl = NCOL - k;
        if (p >= s && p < s + rl) { i = k; j = k + (p - s); }
        s += rl;
    }
    io = i; jo = j;
}

// ---------------------------------------------------------------------------
// k_build: 528 blocks x 384 threads.
// Blocks 0..505: (unordered pair, d-half). Stage the 12x32 d-slice of trans
// rows i,j (2 MLP evals/thread), pack the half's FOLDED pair weights
// (W[ij]+W[ji] off-diag), diag blocks fold the half's linear weights, then
// 288 threads = 144 combos x 2 sub-slices (16-deep) -> LDS combine -> write
// this half's float2 of ptab4[pair][combo]. Blocks 506..527: column norms.
// ---------------------------------------------------------------------------
__global__ __launch_bounds__(384) void k_build(
    const int* __restrict__ features, const float* __restrict__ tables,
    const float* __restrict__ w1, const float* __restrict__ b1,
    const float* __restrict__ w2, const float* __restrict__ b2,
    const float* __restrict__ W_ops, const float* __restrict__ W_concat,
    const float* __restrict__ aw,
    float2* __restrict__ ptab2, float* __restrict__ cn)
{
    int bid = blockIdx.x, tid = threadIdx.x;

    if (bid >= 2 * NUP) {               // ---- column-norm blocks ----
        int i = bid - 2 * NUP;
        __shared__ float ssq[NEMB];
        __shared__ float parts[6];
        if (tid < NEMB) {
            const float* tp = tables + (i * NEMB + tid) * D;
            float s = 0.f;
            #pragma unroll
            for (int d = 0; d < D; ++d) s = fmaf(tp[d], tp[d], s);
            ssq[tid] = s;
        }
        __syncthreads();
        float s = 0.f;
        for (int k = tid; k < BB; k += 384) s += ssq[features[i * BB + k]];
        #pragma unroll
        for (int m = 32; m; m >>= 1) s += __shfl_xor(s, m);
        if ((tid & 63) == 0) parts[tid >> 6] = s;
        __syncthreads();
        if (tid == 0) {
            float t = 0.f;
            #pragma unroll
            for (int q = 0; q < 6; ++q) t += parts[q];
            cn[i] = sqrtf(t);
        }
        return;
    }

    // ---- pair-half blocks ----
    int pair = bid >> 1, h = bid & 1;
    int i, j;
    up_ij(pair, i, j);
    bool diag = (i == j);
    int dbase = h * 32;                   // this block's d-slice

    __shared__ float ti[NEMB][33];
    __shared__ float tj[NEMB][33];
    __shared__ float4 w4s[32];
    __shared__ float wls[2][32];
    __shared__ float2 comb[144][2];

    float b2v = b2[0];
    float a0 = aw[0], a1 = aw[1], a2 = aw[2], a3 = aw[3], a4 = aw[4];
    const float* Wm   = W_ops + 1 * NCOL * NCOL * 2 * D;
    const float* Wmax = W_ops + 2 * NCOL * NCOL * 2 * D;
    const float* Wmin = W_ops + 3 * NCOL * NCOL * 2 * D;

    // stage the d-slice of trans rows i and j: 768 evals, 2 per thread
    for (int k = tid; k < 2 * NEMB * 32; k += 384) {
        int half = (k >= NEMB * 32);
        int kk = k - half * NEMB * 32;         // [0,384): e*32 + dd
        int e = kk >> 5, dd = kk & 31;
        float x = tables[(half ? j : i) * NEMB * D + e * D + dbase + dd];
        float acc = b2v;
        #pragma unroll
        for (int hh = 0; hh < 8; ++hh)
            acc = fmaf(ftanh(fmaf(x, w1[hh], b1[hh])), w2[hh], acc);
        (half ? tj : ti)[e][dd] = acc;
    }

    // pack this half's FOLDED pair weights (threads 0..31)
    if (tid < 32) {
        int d = dbase + tid;
        int pij = i * NCOL + j, pji = j * NCOL + i;
        int a_ij = (pij * 2 + 0) * D + d, b_ij = (pij * 2 + 1) * D + d;
        float4 v;
        if (diag) {
            v.x = a1 * Wm[a_ij];
            v.y = a1 * Wm[b_ij];
            v.z = 0.5f * (a2 * Wmax[a_ij] - a3 * Wmin[a_ij]);
            v.w = 0.5f * (a2 * Wmax[b_ij] - a3 * Wmin[b_ij]);
        } else {
            int a_ji = (pji * 2 + 0) * D + d, b_ji = (pji * 2 + 1) * D + d;
            v.x = a1 * (Wm[a_ij] + Wm[a_ji]);
            v.y = a1 * (Wm[b_ij] + Wm[b_ji]);
            v.z = 0.5f * (a2 * (Wmax[a_ij] + Wmax[a_ji])
                        - a3 * (Wmin[a_ij] + Wmin[a_ji]));
            v.w = 0.5f * (a2 * (Wmax[b_ij] + Wmax[b_ji])
                        - a3 * (Wmin[b_ij] + Wmin[b_ji]));
        }
        w4s[tid] = v;
    }

    // diagonal blocks fold this half's linear weights (threads 64..127)
    if (diag && tid >= 64 && tid < 128) {
        int t = tid - 64;
        int o = t >> 5, dd = t & 31;
        int d = dbase + dd;
        float lp = 0.f, lc = 0.f, lmm = 0.f;
        #pragma unroll
        for (int jj = 0; jj < NCOL; ++jj) {
            int ij = ((i * NCOL + jj) * 2 + o) * D + d;
            int ji = ((jj * NCOL + i) * 2 + o) * D + d;
            lp += W_ops[ij] + W_ops[ji];
            lc += W_concat[((i * NCOL + jj) * 2 + o) * 2 * D + d]
                + W_concat[((jj * NCOL + i) * 2 + o) * 2 * D + D + d];
            lmm += a2 * (Wmax[ij] + Wmax[ji]) + a3 * (Wmin[ij] + Wmin[ji]);
        }
        wls[o][dd] = a0 * lp + a4 * lc + 0.5f * lmm;
    }
    __syncthreads();

    // combos: 288 threads = 144 combos x 2 sub-slices (16-deep each)
    if (tid < 288) {
        int c = tid >> 1, sub = tid & 1;
        int ei = c / NEMB, ej = c - (c / NEMB) * NEMB;
        int d0 = sub * 16;
        bool dl = diag & (ei == ej);
        float r0 = 0.f, r1 = 0.f, l0 = 0.f, l1 = 0.f;
        #pragma unroll
        for (int dd = d0; dd < d0 + 16; ++dd) {
            float a = ti[ei][dd], b = tj[ej][dd];
            float4 w4 = w4s[dd];
            float pp = a * b, dfa = fabsf(a - b);
            r0 = fmaf(pp, w4.x, fmaf(dfa, w4.z, r0));
            r1 = fmaf(pp, w4.y, fmaf(dfa, w4.w, r1));
            if (dl) {
                l0 = fmaf(a, wls[0][dd], l0);
                l1 = fmaf(a, wls[1][dd], l1);
            }
        }
        comb[c][sub] = make_float2(r0 + l0, r1 + l1);
    }
    __syncthreads();
    if (tid < 144) {
        float2 u = comb[tid][0], v = comb[tid][1];
        ptab2[(pair * 144 + tid) * 2 + h] = make_float2(u.x + v.x, u.y + v.y);
    }
}

// ---------------------------------------------------------------------------
// k_gather: 512 blocks x 4 b's (2 blocks/CU). Thread (g,b): g = tid>>2 in
// [0,64) sums its ~4 unordered pairs, one float4 load each (both halves);
// shuffle-reduce the 16 g's per wave, LDS-reduce the 4 waves. Block 0 writes
// the reg scalar.
// ---------------------------------------------------------------------------
__global__ __launch_bounds__(256) void k_gather(const int* __restrict__ features,
        const float4* __restrict__ ptab4, const float* __restrict__ cn,
        float* __restrict__ out)
{
    __shared__ int fs[NCOL][4];
    __shared__ float red[4][4][2];
    __shared__ int lip[NUP], ljp[NUP];
    int tid = threadIdx.x;
    int b0 = blockIdx.x * 4;

    for (int p = tid; p < NUP; p += 256) {
        int ii, jj;
        up_ij(p, ii, jj);
        lip[p] = ii; ljp[p] = jj;
    }
    if (tid >= 256 - NCOL * 4) {              // threads 168..255 stage features
        int k = tid - (256 - NCOL * 4);
        int i = k >> 2, q = k & 3;
        fs[i][q] = features[i * BB + b0 + q];
    }
    __syncthreads();

    int b = tid & 3, g = tid >> 2;            // 64 pair-groups x 4 b's
    int p0 = (g * NUP) >> 6, p1 = ((g + 1) * NUP) >> 6;
    float a0 = 0.f, a1 = 0.f;
    #pragma unroll 2
    for (int p = p0; p < p1; ++p) {
        float4 v = ptab4[p * 144 + fs[lip[p]][b] * NEMB + fs[ljp[p]][b]];
        a0 += v.x + v.z;
        a1 += v.y + v.w;
    }
    // reduce the 16 g's within each wave (lanes differing in bits 2..5)
    #pragma unroll
    for (int m = 4; m <= 32; m <<= 1) {
        a0 += __shfl_xor(a0, m);
        a1 += __shfl_xor(a1, m);
    }
    int w = tid >> 6, lane = tid & 63;
    if (lane < 4) {
        red[w][lane][0] = a0;
        red[w][lane][1] = a1;
    }
    __syncthreads();
    if (tid < 8) {
        int bb = tid >> 1, o = tid & 1;
        out[(b0 + bb) * 2 + o] = red[0][bb][o] + red[1][bb][o]
                               + red[2][bb][o] + red[3][bb][o];
    }
    if (blockIdx.x == 0 && tid == 64) {
        float s = 0.f;
        for (int c = 0; c < NCOL; ++c) s += cn[c];
        out[BB * 2] = REGC * (2.0f * NCOL) * s;
    }
}

extern "C" void kernel_launch(void* const* d_in, const int* in_sizes, int n_in,
                              void* d_out, int out_size, void* d_ws, size_t ws_size,
                              hipStream_t stream) {
    const int*   features = (const int*)d_in[0];
    const float* tables   = (const float*)d_in[1];
    const float* w1       = (const float*)d_in[2];
    const float* b1       = (const float*)d_in[3];
    const float* w2       = (const float*)d_in[4];
    const float* b2       = (const float*)d_in[5];
    const float* W_ops    = (const float*)d_in[6];
    const float* W_concat = (const float*)d_in[7];
    const float* aw       = (const float*)d_in[8];
    float* out = (float*)d_out;
    char*  ws  = (char*)d_ws;

    float2* ptab2 = (float2*)ws;                   // 253*144 float4 = 582,912 B
    float*  cn    = (float*)(ws + 582912);         // 22 f

    k_build <<<dim3(2 * NUP + NCOL), dim3(384), 0, stream>>>(
        features, tables, w1, b1, w2, b2, W_ops, W_concat, aw, ptab2, cn);
    k_gather<<<dim3(512), dim3(256), 0, stream>>>(
        features, (const float4*)ws, cn, out);
}

// Round 16
// 18.140 us; speedup vs baseline: 1.2970x; 1.0624x over previous
//
#include <hip/hip_runtime.h>
#include <math.h>

#define NCOL 22
#define NEMB 12
#define D 64
#define BB 2048
#define NUP 253             // unordered pairs incl. diagonal: 22*23/2
#define REGC 0.001f

__device__ __forceinline__ float ftanh(float x) {
    float cx = fminf(fmaxf(x, -10.f), 10.f);
    float e = __expf(2.f * cx);
    return (e - 1.f) / (e + 1.f);
}

// p -> (i,j), i<=j, triangular-with-diagonal order (p in [0,253))
__device__ __forceinline__ void up_ij(int p, int& io, int& jo) {
    int s = 0, i = 0, j = 0;
    #pragma unroll
    for (int k = 0; k < NCOL; ++k) {
        int rl = NCOL - k;
        if (p >= s && p < s + rl) { i = k; j = k + (p - s); }
        s += rl;
    }
    io = i; jo = j;
}

// ---------------------------------------------------------------------------
// k_build: 528 blocks x 768 threads.
// Blocks 0..505: (unordered pair, d-half). Stage the 12x32 d-slice of trans
// rows i,j -- EXACTLY 1 MLP eval per thread. Pack the half's FOLDED pair
// weights, diag blocks fold the half's linear weights, then 576 threads =
// 144 combos x 4 sub-slices (8-deep) -> LDS combine -> write this half's
// float2 of ptab4[pair][combo]. Blocks 506..527: column norms.
// ---------------------------------------------------------------------------
__global__ __launch_bounds__(768) void k_build(
    const int* __restrict__ features, const float* __restrict__ tables,
    const float* __restrict__ w1, const float* __restrict__ b1,
    const float* __restrict__ w2, const float* __restrict__ b2,
    const float* __restrict__ W_ops, const float* __restrict__ W_concat,
    const float* __restrict__ aw,
    float2* __restrict__ ptab2, float* __restrict__ cn)
{
    int bid = blockIdx.x, tid = threadIdx.x;

    if (bid >= 2 * NUP) {               // ---- column-norm blocks ----
        int i = bid - 2 * NUP;
        __shared__ float ssq[NEMB];
        __shared__ float parts[12];
        if (tid < NEMB) {
            const float* tp = tables + (i * NEMB + tid) * D;
            float s = 0.f;
            #pragma unroll
            for (int d = 0; d < D; ++d) s = fmaf(tp[d], tp[d], s);
            ssq[tid] = s;
        }
        __syncthreads();
        float s = 0.f;
        for (int k = tid; k < BB; k += 768) s += ssq[features[i * BB + k]];
        #pragma unroll
        for (int m = 32; m; m >>= 1) s += __shfl_xor(s, m);
        if ((tid & 63) == 0) parts[tid >> 6] = s;
        __syncthreads();
        if (tid == 0) {
            float t = 0.f;
            #pragma unroll
            for (int q = 0; q < 12; ++q) t += parts[q];
            cn[i] = sqrtf(t);
        }
        return;
    }

    // ---- pair-half blocks ----
    int pair = bid >> 1, h = bid & 1;
    int i, j;
    up_ij(pair, i, j);
    bool diag = (i == j);
    int dbase = h * 32;                   // this block's d-slice

    __shared__ float ti[NEMB][33];
    __shared__ float tj[NEMB][33];
    __shared__ float4 w4s[32];
    __shared__ float wls[2][32];
    __shared__ float2 comb[144][4];

    float b2v = b2[0];
    float a0 = aw[0], a1 = aw[1], a2 = aw[2], a3 = aw[3], a4 = aw[4];
    const float* Wm   = W_ops + 1 * NCOL * NCOL * 2 * D;
    const float* Wmax = W_ops + 2 * NCOL * NCOL * 2 * D;
    const float* Wmin = W_ops + 3 * NCOL * NCOL * 2 * D;

    // stage the d-slice of trans rows i and j: 768 evals, 1 per thread
    {
        int k = tid;                           // [0,768)
        int half = (k >= NEMB * 32);
        int kk = k - half * NEMB * 32;         // [0,384): e*32 + dd
        int e = kk >> 5, dd = kk & 31;
        float x = tables[(half ? j : i) * NEMB * D + e * D + dbase + dd];
        float acc = b2v;
        #pragma unroll
        for (int hh = 0; hh < 8; ++hh)
            acc = fmaf(ftanh(fmaf(x, w1[hh], b1[hh])), w2[hh], acc);
        (half ? tj : ti)[e][dd] = acc;
    }

    // pack this half's FOLDED pair weights (threads 0..31 do global loads
    // concurrently with other threads' MLP -- independent issue)
    if (tid < 32) {
        int d = dbase + tid;
        int pij = i * NCOL + j, pji = j * NCOL + i;
        int a_ij = (pij * 2 + 0) * D + d, b_ij = (pij * 2 + 1) * D + d;
        float4 v;
        if (diag) {
            v.x = a1 * Wm[a_ij];
            v.y = a1 * Wm[b_ij];
            v.z = 0.5f * (a2 * Wmax[a_ij] - a3 * Wmin[a_ij]);
            v.w = 0.5f * (a2 * Wmax[b_ij] - a3 * Wmin[b_ij]);
        } else {
            int a_ji = (pji * 2 + 0) * D + d, b_ji = (pji * 2 + 1) * D + d;
            v.x = a1 * (Wm[a_ij] + Wm[a_ji]);
            v.y = a1 * (Wm[b_ij] + Wm[b_ji]);
            v.z = 0.5f * (a2 * (Wmax[a_ij] + Wmax[a_ji])
                        - a3 * (Wmin[a_ij] + Wmin[a_ji]));
            v.w = 0.5f * (a2 * (Wmax[b_ij] + Wmax[b_ji])
                        - a3 * (Wmin[b_ij] + Wmin[b_ji]));
        }
        w4s[tid] = v;
    }

    // diagonal blocks fold this half's linear weights (threads 64..127)
    if (diag && tid >= 64 && tid < 128) {
        int t = tid - 64;
        int o = t >> 5, dd = t & 31;
        int d = dbase + dd;
        float lp = 0.f, lc = 0.f, lmm = 0.f;
        #pragma unroll
        for (int jj = 0; jj < NCOL; ++jj) {
            int ij = ((i * NCOL + jj) * 2 + o) * D + d;
            int ji = ((jj * NCOL + i) * 2 + o) * D + d;
            lp += W_ops[ij] + W_ops[ji];
            lc += W_concat[((i * NCOL + jj) * 2 + o) * 2 * D + d]
                + W_concat[((jj * NCOL + i) * 2 + o) * 2 * D + D + d];
            lmm += a2 * (Wmax[ij] + Wmax[ji]) + a3 * (Wmin[ij] + Wmin[ji]);
        }
        wls[o][dd] = a0 * lp + a4 * lc + 0.5f * lmm;
    }
    __syncthreads();

    // combos: 576 threads = 144 combos x 4 sub-slices (8-deep each)
    if (tid < 576) {
        int c = tid >> 2, sub = tid & 3;
        int ei = c / NEMB, ej = c - (c / NEMB) * NEMB;
        int d0 = sub * 8;
        bool dl = diag & (ei == ej);
        float r0 = 0.f, r1 = 0.f, l0 = 0.f, l1 = 0.f;
        #pragma unroll
        for (int dd = d0; dd < d0 + 8; ++dd) {
            float a = ti[ei][dd], b = tj[ej][dd];
            float4 w4 = w4s[dd];
            float pp = a * b, dfa = fabsf(a - b);
            r0 = fmaf(pp, w4.x, fmaf(dfa, w4.z, r0));
            r1 = fmaf(pp, w4.y, fmaf(dfa, w4.w, r1));
            if (dl) {
                l0 = fmaf(a, wls[0][dd], l0);
                l1 = fmaf(a, wls[1][dd], l1);
            }
        }
        comb[c][sub] = make_float2(r0 + l0, r1 + l1);
    }
    __syncthreads();
    if (tid < 144) {
        float2 u0 = comb[tid][0], u1 = comb[tid][1];
        float2 u2 = comb[tid][2], u3 = comb[tid][3];
        ptab2[(pair * 144 + tid) * 2 + h] =
            make_float2(u0.x + u1.x + u2.x + u3.x,
                        u0.y + u1.y + u2.y + u3.y);
    }
}

// ---------------------------------------------------------------------------
// k_gather: 512 blocks x 4 b's (2 blocks/CU). Thread (g,b): g = tid>>2 in
// [0,64) sums its ~4 unordered pairs, one float4 load each (both halves);
// shuffle-reduce the 16 g's per wave, LDS-reduce the 4 waves. Block 0 writes
// the reg scalar. (unchanged from round 15 -- proven)
// ---------------------------------------------------------------------------
__global__ __launch_bounds__(256) void k_gather(const int* __restrict__ features,
        const float4* __restrict__ ptab4, const float* __restrict__ cn,
        float* __restrict__ out)
{
    __shared__ int fs[NCOL][4];
    __shared__ float red[4][4][2];
    __shared__ int lip[NUP], ljp[NUP];
    int tid = threadIdx.x;
    int b0 = blockIdx.x * 4;

    for (int p = tid; p < NUP; p += 256) {
        int ii, jj;
        up_ij(p, ii, jj);
        lip[p] = ii; ljp[p] = jj;
    }
    if (tid >= 256 - NCOL * 4) {              // threads 168..255 stage features
        int k = tid - (256 - NCOL * 4);
        int i = k >> 2, q = k & 3;
        fs[i][q] = features[i * BB + b0 + q];
    }
    __syncthreads();

    int b = tid & 3, g = tid >> 2;            // 64 pair-groups x 4 b's
    int p0 = (g * NUP) >> 6, p1 = ((g + 1) * NUP) >> 6;
    float a0 = 0.f, a1 = 0.f;
    #pragma unroll 2
    for (int p = p0; p < p1; ++p) {
        float4 v = ptab4[p * 144 + fs[lip[p]][b] * NEMB + fs[ljp[p]][b]];
        a0 += v.x + v.z;
        a1 += v.y + v.w;
    }
    // reduce the 16 g's within each wave (lanes differing in bits 2..5)
    #pragma unroll
    for (int m = 4; m <= 32; m <<= 1) {
        a0 += __shfl_xor(a0, m);
        a1 += __shfl_xor(a1, m);
    }
    int w = tid >> 6, lane = tid & 63;
    if (lane < 4) {
        red[w][lane][0] = a0;
        red[w][lane][1] = a1;
    }
    __syncthreads();
    if (tid < 8) {
        int bb = tid >> 1, o = tid & 1;
        out[(b0 + bb) * 2 + o] = red[0][bb][o] + red[1][bb][o]
                               + red[2][bb][o] + red[3][bb][o];
    }
    if (blockIdx.x == 0 && tid == 64) {
        float s = 0.f;
        for (int c = 0; c < NCOL; ++c) s += cn[c];
        out[BB * 2] = REGC * (2.0f * NCOL) * s;
    }
}

extern "C" void kernel_launch(void* const* d_in, const int* in_sizes, int n_in,
                              void* d_out, int out_size, void* d_ws, size_t ws_size,
                              hipStream_t stream) {
    const int*   features = (const int*)d_in[0];
    const float* tables   = (const float*)d_in[1];
    const float* w1       = (const float*)d_in[2];
    const float* b1       = (const float*)d_in[3];
    const float* w2       = (const float*)d_in[4];
    const float* b2       = (const float*)d_in[5];
    const float* W_ops    = (const float*)d_in[6];
    const float* W_concat = (const float*)d_in[7];
    const float* aw       = (const float*)d_in[8];
    float* out = (float*)d_out;
    char*  ws  = (char*)d_ws;

    float2* ptab2 = (float2*)ws;                   // 253*144 float4 = 582,912 B
    float*  cn    = (float*)(ws + 582912);         // 22 f

    k_build <<<dim3(2 * NUP + NCOL), dim3(768), 0, stream>>>(
        features, tables, w1, b1, w2, b2, W_ops, W_concat, aw, ptab2, cn);
    k_gather<<<dim3(512), dim3(256), 0, stream>>>(
        features, (const float4*)ws, cn, out);
}

// Round 17
// 14.848 us; speedup vs baseline: 1.5846x; 1.2217x over previous
//
#include <hip/hip_runtime.h>
#include <math.h>

#define NCOL 22
#define NEMB 12
#define D 64
#define BB 2048
#define NUP 253             // unordered pairs incl. diagonal: 22*23/2
#define REGC 0.001f

__device__ __forceinline__ float ftanh(float x) {
    float cx = fminf(fmaxf(x, -10.f), 10.f);
    float e = __expf(2.f * cx);
    return (e - 1.f) * __builtin_amdgcn_rcpf(e + 1.f);
}

// p -> (i,j), i<=j, triangular order. Row starts s_i = i*(45-i)/2;
// 2025-8*s_i = (45-2i)^2 exact in fp32, so boundaries are exact.
__device__ __forceinline__ void up_ij(int p, int& io, int& jo) {
    int i = (int)((45.0f - sqrtf(2025.0f - 8.0f * (float)p)) * 0.5f);
    int s = (i * (45 - i)) >> 1;
    if (p < s)                 { --i; s = (i * (45 - i)) >> 1; }
    else if (p - s >= NCOL - i){ ++i; s = (i * (45 - i)) >> 1; }
    io = i; jo = i + (p - s);
}

// ---------------------------------------------------------------------------
// k_build: exactly 512 blocks x 768 threads (2 blocks/CU, no tail).
// Blocks 0..505: (unordered pair, d-half). 1 MLP eval/thread staging; FOLDED
// pair weights; diag blocks fold linear weights with 704-thread partials +
// 64-thread LDS reduce (extra block-uniform barrier); 576-thread combo
// (144 x 4 sub-slices, 8-deep). Blocks 506..511: colnorms, 4 columns each.
// ---------------------------------------------------------------------------
__global__ __launch_bounds__(768) void k_build(
    const int* __restrict__ features, const float* __restrict__ tables,
    const float* __restrict__ w1, const float* __restrict__ b1,
    const float* __restrict__ w2, const float* __restrict__ b2,
    const float* __restrict__ W_ops, const float* __restrict__ W_concat,
    const float* __restrict__ aw,
    float2* __restrict__ ptab2, float* __restrict__ cn)
{
    int bid = blockIdx.x, tid = threadIdx.x;

    if (bid >= 2 * NUP) {               // ---- colnorm blocks (4 cols each) --
        int cb = bid - 2 * NUP;         // 0..5
        int grp = tid / 192, lt = tid - grp * 192;   // 4 groups x 3 waves
        int col = cb * 4 + grp;
        __shared__ float ssq4[4][NEMB];
        __shared__ float parts[4][3];
        if (col < NCOL && lt < NEMB) {
            const float* tp = tables + (col * NEMB + lt) * D;
            float s = 0.f;
            #pragma unroll
            for (int d = 0; d < D; ++d) s = fmaf(tp[d], tp[d], s);
            ssq4[grp][lt] = s;
        }
        __syncthreads();
        if (col < NCOL) {
            float s = 0.f;
            for (int k = lt; k < BB; k += 192) s += ssq4[grp][features[col * BB + k]];
            #pragma unroll
            for (int m = 32; m; m >>= 1) s += __shfl_xor(s, m);
            if ((lt & 63) == 0) parts[grp][lt >> 6] = s;
        }
        __syncthreads();
        if (col < NCOL && lt == 0)
            cn[col] = sqrtf(parts[grp][0] + parts[grp][1] + parts[grp][2]);
        return;
    }

    // ---- pair-half blocks ----
    int pair = bid >> 1, h = bid & 1;
    int i, j;
    up_ij(pair, i, j);
    bool diag = (i == j);
    int dbase = h * 32;

    __shared__ float ti[NEMB][33];
    __shared__ float tj[NEMB][33];
    __shared__ float4 w4s[32];
    __shared__ float wls[2][32];
    __shared__ float2 comb[144][4];
    __shared__ float fold[NCOL][2][32];   // diag-only partials

    float b2v = b2[0];
    float a0 = aw[0], a1 = aw[1], a2 = aw[2], a3 = aw[3], a4 = aw[4];
    const float* Wm   = W_ops + 1 * NCOL * NCOL * 2 * D;
    const float* Wmax = W_ops + 2 * NCOL * NCOL * 2 * D;
    const float* Wmin = W_ops + 3 * NCOL * NCOL * 2 * D;

    // stage the d-slice of trans rows i and j: 768 evals, 1 per thread
    {
        int k = tid;
        int half = (k >= NEMB * 32);
        int kk = k - half * NEMB * 32;
        int e = kk >> 5, dd = kk & 31;
        float x = tables[(half ? j : i) * NEMB * D + e * D + dbase + dd];
        float acc = b2v;
        #pragma unroll
        for (int hh = 0; hh < 8; ++hh)
            acc = fmaf(ftanh(fmaf(x, w1[hh], b1[hh])), w2[hh], acc);
        (half ? tj : ti)[e][dd] = acc;
    }

    // pack this half's FOLDED pair weights (threads 0..31)
    if (tid < 32) {
        int d = dbase + tid;
        int pij = i * NCOL + j, pji = j * NCOL + i;
        int a_ij = (pij * 2 + 0) * D + d, b_ij = (pij * 2 + 1) * D + d;
        float4 v;
        if (diag) {
            v.x = a1 * Wm[a_ij];
            v.y = a1 * Wm[b_ij];
            v.z = 0.5f * (a2 * Wmax[a_ij] - a3 * Wmin[a_ij]);
            v.w = 0.5f * (a2 * Wmax[b_ij] - a3 * Wmin[b_ij]);
        } else {
            int a_ji = (pji * 2 + 0) * D + d, b_ji = (pji * 2 + 1) * D + d;
            v.x = a1 * (Wm[a_ij] + Wm[a_ji]);
            v.y = a1 * (Wm[b_ij] + Wm[b_ji]);
            v.z = 0.5f * (a2 * (Wmax[a_ij] + Wmax[a_ji])
                        - a3 * (Wmin[a_ij] + Wmin[a_ji]));
            v.w = 0.5f * (a2 * (Wmax[b_ij] + Wmax[b_ji])
                        - a3 * (Wmin[b_ij] + Wmin[b_ji]));
        }
        w4s[tid] = v;
    }

    // diag: 704 threads compute per-jj fold partials (16 loads each)
    if (diag && tid < NCOL * 32) {
        int jj = tid >> 5, dd = tid & 31;
        int d = dbase + dd;
        #pragma unroll
        for (int o = 0; o < 2; ++o) {
            int ij = ((i * NCOL + jj) * 2 + o) * D + d;
            int ji = ((jj * NCOL + i) * 2 + o) * D + d;
            float lp = W_ops[ij] + W_ops[ji];
            float lc = W_concat[((i * NCOL + jj) * 2 + o) * 2 * D + d]
                     + W_concat[((jj * NCOL + i) * 2 + o) * 2 * D + D + d];
            float lmm = a2 * (Wmax[ij] + Wmax[ji]) + a3 * (Wmin[ij] + Wmin[ji]);
            fold[jj][o][dd] = a0 * lp + a4 * lc + 0.5f * lmm;
        }
    }
    __syncthreads();

    if (diag) {                           // block-uniform branch: barrier legal
        if (tid < 64) {
            int o = tid >> 5, dd = tid & 31;
            float s = 0.f;
            #pragma unroll
            for (int jj = 0; jj < NCOL; ++jj) s += fold[jj][o][dd];
            wls[o][dd] = s;
        }
        __syncthreads();
    }

    // combos: 576 threads = 144 combos x 4 sub-slices (8-deep each)
    if (tid < 576) {
        int c = tid >> 2, sub = tid & 3;
        int ei = c / NEMB, ej = c - (c / NEMB) * NEMB;
        int d0 = sub * 8;
        bool dl = diag & (ei == ej);
        float r0 = 0.f, r1 = 0.f, l0 = 0.f, l1 = 0.f;
        #pragma unroll
        for (int dd = d0; dd < d0 + 8; ++dd) {
            float a = ti[ei][dd], b = tj[ej][dd];
            float4 w4 = w4s[dd];
            float pp = a * b, dfa = fabsf(a - b);
            r0 = fmaf(pp, w4.x, fmaf(dfa, w4.z, r0));
            r1 = fmaf(pp, w4.y, fmaf(dfa, w4.w, r1));
            if (dl) {
                l0 = fmaf(a, wls[0][dd], l0);
                l1 = fmaf(a, wls[1][dd], l1);
            }
        }
        comb[c][sub] = make_float2(r0 + l0, r1 + l1);
    }
    __syncthreads();
    if (tid < 144) {
        float2 u0 = comb[tid][0], u1 = comb[tid][1];
        float2 u2 = comb[tid][2], u3 = comb[tid][3];
        ptab2[(pair * 144 + tid) * 2 + h] =
            make_float2(u0.x + u1.x + u2.x + u3.x,
                        u0.y + u1.y + u2.y + u3.y);
    }
}

// ---------------------------------------------------------------------------
// k_gather: 512 blocks x 4 b's (2 blocks/CU). Thread (g,b): g = tid>>2 sums
// its ~4 unordered pairs (one float4 each), (i,j) via closed form (no LUT);
// shuffle-reduce 16 g's per wave, LDS-reduce 4 waves. Block 0 writes regs.
// ---------------------------------------------------------------------------
__global__ __launch_bounds__(256) void k_gather(const int* __restrict__ features,
        const float4* __restrict__ ptab4, const float* __restrict__ cn,
        float* __restrict__ out)
{
    __shared__ int fs[NCOL][4];
    __shared__ float red[4][4][2];
    int tid = threadIdx.x;
    int b0 = blockIdx.x * 4;

    if (tid < NCOL * 4) {
        int i = tid >> 2, q = tid & 3;
        fs[i][q] = features[i * BB + b0 + q];
    }
    __syncthreads();

    int b = tid & 3, g = tid >> 2;            // 64 pair-groups x 4 b's
    int p0 = (g * NUP) >> 6, p1 = ((g + 1) * NUP) >> 6;
    float a0 = 0.f, a1 = 0.f;
    #pragma unroll 2
    for (int p = p0; p < p1; ++p) {
        int ii, jj;
        up_ij(p, ii, jj);
        float4 v = ptab4[p * 144 + fs[ii][b] * NEMB + fs[jj][b]];
        a0 += v.x + v.z;
        a1 += v.y + v.w;
    }
    #pragma unroll
    for (int m = 4; m <= 32; m <<= 1) {
        a0 += __shfl_xor(a0, m);
        a1 += __shfl_xor(a1, m);
    }
    int w = tid >> 6, lane = tid & 63;
    if (lane < 4) {
        red[w][lane][0] = a0;
        red[w][lane][1] = a1;
    }
    __syncthreads();
    if (tid < 8) {
        int bb = tid >> 1, o = tid & 1;
        out[(b0 + bb) * 2 + o] = red[0][bb][o] + red[1][bb][o]
                               + red[2][bb][o] + red[3][bb][o];
    }
    if (blockIdx.x == 0 && tid == 64) {
        float s = 0.f;
        for (int c = 0; c < NCOL; ++c) s += cn[c];
        out[BB * 2] = REGC * (2.0f * NCOL) * s;
    }
}

extern "C" void kernel_launch(void* const* d_in, const int* in_sizes, int n_in,
                              void* d_out, int out_size, void* d_ws, size_t ws_size,
                              hipStream_t stream) {
    const int*   features = (const int*)d_in[0];
    const float* tables   = (const float*)d_in[1];
    const float* w1       = (const float*)d_in[2];
    const float* b1       = (const float*)d_in[3];
    const float* w2       = (const float*)d_in[4];
    const float* b2       = (const float*)d_in[5];
    const float* W_ops    = (const float*)d_in[6];
    const float* W_concat = (const float*)d_in[7];
    const float* aw       = (const float*)d_in[8];
    float* out = (float*)d_out;
    char*  ws  = (char*)d_ws;

    float2* ptab2 = (float2*)ws;                   // 253*144 float4 = 582,912 B
    float*  cn    = (float*)(ws + 582912);         // 22 f

    k_build <<<dim3(512), dim3(768), 0, stream>>>(
        features, tables, w1, b1, w2, b2, W_ops, W_concat, aw, ptab2, cn);
    k_gather<<<dim3(512), dim3(256), 0, stream>>>(
        features, (const float4*)ws, cn, out);
}

// Round 18
// 14.636 us; speedup vs baseline: 1.6075x; 1.0145x over previous
//
#include <hip/hip_runtime.h>
#include <math.h>

#define NCOL 22
#define NEMB 12
#define D 64
#define BB 2048
#define NUP 253             // unordered pairs incl. diagonal: 22*23/2
#define REGC 0.001f
#define L2E2 2.885390082f   // 2*log2(e)

// p -> (i,j), i<=j, triangular order. Row starts s_i = i*(45-i)/2;
// 2025-8*s_i = (45-2i)^2 exact in fp32, so boundaries are exact.
__device__ __forceinline__ void up_ij(int p, int& io, int& jo) {
    int i = (int)((45.0f - sqrtf(2025.0f - 8.0f * (float)p)) * 0.5f);
    int s = (i * (45 - i)) >> 1;
    if (p < s)                 { --i; s = (i * (45 - i)) >> 1; }
    else if (p - s >= NCOL - i){ ++i; s = (i * (45 - i)) >> 1; }
    io = i; jo = i + (p - s);
}

// ---------------------------------------------------------------------------
// k_build: exactly 512 blocks x 768 threads (2 blocks/CU, no tail).
// Blocks 0..505: (unordered pair, d-half). 1 MLP eval/thread staging with
// exp2-folded constants (no clamp: |x*w1+b1| <= ~1 for these input scales,
// overflow needs |y|>43); FOLDED pair weights; diag fold spread over 704
// threads; 576-thread combo. Blocks 506..511: colnorms, 4 columns each.
// ---------------------------------------------------------------------------
__global__ __launch_bounds__(768) void k_build(
    const int* __restrict__ features, const float* __restrict__ tables,
    const float* __restrict__ w1, const float* __restrict__ b1,
    const float* __restrict__ w2, const float* __restrict__ b2,
    const float* __restrict__ W_ops, const float* __restrict__ W_concat,
    const float* __restrict__ aw,
    float2* __restrict__ ptab2, float* __restrict__ cn)
{
    int bid = blockIdx.x, tid = threadIdx.x;

    if (bid >= 2 * NUP) {               // ---- colnorm blocks (4 cols each) --
        int cb = bid - 2 * NUP;         // 0..5
        int grp = tid / 192, lt = tid - grp * 192;   // 4 groups x 3 waves
        int col = cb * 4 + grp;
        __shared__ float ssq4[4][NEMB];
        __shared__ float parts[4][3];
        if (col < NCOL && lt < NEMB) {
            const float* tp = tables + (col * NEMB + lt) * D;
            float s = 0.f;
            #pragma unroll
            for (int d = 0; d < D; ++d) s = fmaf(tp[d], tp[d], s);
            ssq4[grp][lt] = s;
        }
        __syncthreads();
        if (col < NCOL) {
            float s = 0.f;
            for (int k = lt; k < BB; k += 192) s += ssq4[grp][features[col * BB + k]];
            #pragma unroll
            for (int m = 32; m; m >>= 1) s += __shfl_xor(s, m);
            if ((lt & 63) == 0) parts[grp][lt >> 6] = s;
        }
        __syncthreads();
        if (col < NCOL && lt == 0)
            cn[col] = sqrtf(parts[grp][0] + parts[grp][1] + parts[grp][2]);
        return;
    }

    // ---- pair-half blocks ----
    int pair = bid >> 1, h = bid & 1;
    int i, j;
    up_ij(pair, i, j);
    bool diag = (i == j);
    int dbase = h * 32;

    __shared__ float ti[NEMB][33];
    __shared__ float tj[NEMB][33];
    __shared__ float4 w4s[32];
    __shared__ float wls[2][32];
    __shared__ float2 comb[144][4];
    __shared__ float fold[NCOL][2][32];   // diag-only partials

    float b2v = b2[0];
    float a0 = aw[0], a1 = aw[1], a2 = aw[2], a3 = aw[3], a4 = aw[4];
    const float* Wm   = W_ops + 1 * NCOL * NCOL * 2 * D;
    const float* Wmax = W_ops + 2 * NCOL * NCOL * 2 * D;
    const float* Wmin = W_ops + 3 * NCOL * NCOL * 2 * D;

    // exp2-folded MLP constants (uniform -> SGPR)
    float w1s[8], b1s[8], w2v[8];
    #pragma unroll
    for (int hh = 0; hh < 8; ++hh) {
        w1s[hh] = w1[hh] * L2E2;
        b1s[hh] = b1[hh] * L2E2;
        w2v[hh] = w2[hh];
    }

    // stage the d-slice of trans rows i and j: 768 evals, 1 per thread
    {
        int k = tid;
        int half = (k >= NEMB * 32);
        int kk = k - half * NEMB * 32;
        int e = kk >> 5, dd = kk & 31;
        float x = tables[(half ? j : i) * NEMB * D + e * D + dbase + dd];
        float acc = b2v;
        #pragma unroll
        for (int hh = 0; hh < 8; ++hh) {
            float ex = __builtin_amdgcn_exp2f(fmaf(x, w1s[hh], b1s[hh]));
            float t = (ex - 1.f) * __builtin_amdgcn_rcpf(ex + 1.f);
            acc = fmaf(t, w2v[hh], acc);
        }
        (half ? tj : ti)[e][dd] = acc;
    }

    // pack this half's FOLDED pair weights (threads 0..31)
    if (tid < 32) {
        int d = dbase + tid;
        int pij = i * NCOL + j, pji = j * NCOL + i;
        int a_ij = (pij * 2 + 0) * D + d, b_ij = (pij * 2 + 1) * D + d;
        float4 v;
        if (diag) {
            v.x = a1 * Wm[a_ij];
            v.y = a1 * Wm[b_ij];
            v.z = 0.5f * (a2 * Wmax[a_ij] - a3 * Wmin[a_ij]);
            v.w = 0.5f * (a2 * Wmax[b_ij] - a3 * Wmin[b_ij]);
        } else {
            int a_ji = (pji * 2 + 0) * D + d, b_ji = (pji * 2 + 1) * D + d;
            v.x = a1 * (Wm[a_ij] + Wm[a_ji]);
            v.y = a1 * (Wm[b_ij] + Wm[b_ji]);
            v.z = 0.5f * (a2 * (Wmax[a_ij] + Wmax[a_ji])
                        - a3 * (Wmin[a_ij] + Wmin[a_ji]));
            v.w = 0.5f * (a2 * (Wmax[b_ij] + Wmax[b_ji])
                        - a3 * (Wmin[b_ij] + Wmin[b_ji]));
        }
        w4s[tid] = v;
    }

    // diag: 704 threads compute per-jj fold partials (16 loads each)
    if (diag && tid < NCOL * 32) {
        int jj = tid >> 5, dd = tid & 31;
        int d = dbase + dd;
        #pragma unroll
        for (int o = 0; o < 2; ++o) {
            int ij = ((i * NCOL + jj) * 2 + o) * D + d;
            int ji = ((jj * NCOL + i) * 2 + o) * D + d;
            float lp = W_ops[ij] + W_ops[ji];
            float lc = W_concat[((i * NCOL + jj) * 2 + o) * 2 * D + d]
                     + W_concat[((jj * NCOL + i) * 2 + o) * 2 * D + D + d];
            float lmm = a2 * (Wmax[ij] + Wmax[ji]) + a3 * (Wmin[ij] + Wmin[ji]);
            fold[jj][o][dd] = a0 * lp + a4 * lc + 0.5f * lmm;
        }
    }
    __syncthreads();

    if (diag) {                           // block-uniform branch: barrier legal
        if (tid < 64) {
            int o = tid >> 5, dd = tid & 31;
            float s = 0.f;
            #pragma unroll
            for (int jj = 0; jj < NCOL; ++jj) s += fold[jj][o][dd];
            wls[o][dd] = s;
        }
        __syncthreads();
    }

    // combos: 576 threads = 144 combos x 4 sub-slices (8-deep each)
    if (tid < 576) {
        int c = tid >> 2, sub = tid & 3;
        int ei = c / NEMB, ej = c - (c / NEMB) * NEMB;
        int d0 = sub * 8;
        bool dl = diag & (ei == ej);
        float r0 = 0.f, r1 = 0.f, l0 = 0.f, l1 = 0.f;
        #pragma unroll
        for (int dd = d0; dd < d0 + 8; ++dd) {
            float a = ti[ei][dd], b = tj[ej][dd];
            float4 w4 = w4s[dd];
            float pp = a * b, dfa = fabsf(a - b);
            r0 = fmaf(pp, w4.x, fmaf(dfa, w4.z, r0));
            r1 = fmaf(pp, w4.y, fmaf(dfa, w4.w, r1));
            if (dl) {
                l0 = fmaf(a, wls[0][dd], l0);
                l1 = fmaf(a, wls[1][dd], l1);
            }
        }
        comb[c][sub] = make_float2(r0 + l0, r1 + l1);
    }
    __syncthreads();
    if (tid < 144) {
        float2 u0 = comb[tid][0], u1 = comb[tid][1];
        float2 u2 = comb[tid][2], u3 = comb[tid][3];
        ptab2[(pair * 144 + tid) * 2 + h] =
            make_float2(u0.x + u1.x + u2.x + u3.x,
                        u0.y + u1.y + u2.y + u3.y);
    }
}

// ---------------------------------------------------------------------------
// k_gather: 1024 blocks x 2 b's (4 blocks/CU = 16 waves/CU, 2x the TLP of
// the 512-block version). Thread (g,b): g = tid>>1 in [0,128) sums ~2 pairs
// (one float4 each, both halves); shuffle-reduce the 32 g's per wave,
// LDS-reduce the 4 waves. Block 0 writes the reg scalar.
// ---------------------------------------------------------------------------
__global__ __launch_bounds__(256) void k_gather(const int* __restrict__ features,
        const float4* __restrict__ ptab4, const float* __restrict__ cn,
        float* __restrict__ out)
{
    __shared__ int fs[NCOL][2];
    __shared__ float red[4][2][2];
    int tid = threadIdx.x;
    int b0 = blockIdx.x * 2;

    if (tid < NCOL * 2) {
        int i = tid >> 1, q = tid & 1;
        fs[i][q] = features[i * BB + b0 + q];
    }
    __syncthreads();

    int b = tid & 1, g = tid >> 1;            // 128 pair-groups x 2 b's
    int p0 = (g * NUP) >> 7, p1 = ((g + 1) * NUP) >> 7;
    float a0 = 0.f, a1 = 0.f;
    #pragma unroll 2
    for (int p = p0; p < p1; ++p) {
        int ii, jj;
        up_ij(p, ii, jj);
        float4 v = ptab4[p * 144 + fs[ii][b] * NEMB + fs[jj][b]];
        a0 += v.x + v.z;
        a1 += v.y + v.w;
    }
    // reduce the 32 g's within each wave (lanes differing in bits 1..5)
    #pragma unroll
    for (int m = 2; m <= 32; m <<= 1) {
        a0 += __shfl_xor(a0, m);
        a1 += __shfl_xor(a1, m);
    }
    int w = tid >> 6, lane = tid & 63;
    if (lane < 2) {
        red[w][lane][0] = a0;
        red[w][lane][1] = a1;
    }
    __syncthreads();
    if (tid < 4) {
        int bb = tid >> 1, o = tid & 1;
        out[(b0 + bb) * 2 + o] = red[0][bb][o] + red[1][bb][o]
                               + red[2][bb][o] + red[3][bb][o];
    }
    if (blockIdx.x == 0 && tid == 64) {
        float s = 0.f;
        for (int c = 0; c < NCOL; ++c) s += cn[c];
        out[BB * 2] = REGC * (2.0f * NCOL) * s;
    }
}

extern "C" void kernel_launch(void* const* d_in, const int* in_sizes, int n_in,
                              void* d_out, int out_size, void* d_ws, size_t ws_size,
                              hipStream_t stream) {
    const int*   features = (const int*)d_in[0];
    const float* tables   = (const float*)d_in[1];
    const float* w1       = (const float*)d_in[2];
    const float* b1       = (const float*)d_in[3];
    const float* w2       = (const float*)d_in[4];
    const float* b2       = (const float*)d_in[5];
    const float* W_ops    = (const float*)d_in[6];
    const float* W_concat = (const float*)d_in[7];
    const float* aw       = (const float*)d_in[8];
    float* out = (float*)d_out;
    char*  ws  = (char*)d_ws;

    float2* ptab2 = (float2*)ws;                   // 253*144 float4 = 582,912 B
    float*  cn    = (float*)(ws + 582912);         // 22 f

    k_build <<<dim3(512),  dim3(768), 0, stream>>>(
        features, tables, w1, b1, w2, b2, W_ops, W_concat, aw, ptab2, cn);
    k_gather<<<dim3(1024), dim3(256), 0, stream>>>(
        features, (const float4*)ws, cn, out);
}